// Round 1
// baseline (40.428 us; speedup 1.0000x reference)
//
#include <hip/hip_runtime.h>

// Problem constants (from reference)
#define B_    16
#define N_    8192
#define FEAT_ 256
#define MEM_  128
#define U_    512

#define NCHUNK 64
#define ROWS_PER_CHUNK (N_ / NCHUNK)   // 128 rows per block

// ---------------------------------------------------------------------------
// Kernel 1: partial column sums of X over the N axis.
//   X: [B, N, FEAT] fp32 row-major.
//   part: [NCHUNK][B][FEAT] fp32 partial sums.
// grid = (NCHUNK, B), block = 256 threads.
// Each wave's 64 lanes read one full row (64 * float4 = 1024 B) -> perfectly
// coalesced. 4 row-phases per block combined via LDS (no float atomics ->
// bitwise deterministic).
// ---------------------------------------------------------------------------
__global__ __launch_bounds__(256) void colsum_partial(
    const float* __restrict__ X, float* __restrict__ part) {
    const int chunk = blockIdx.x;
    const int b     = blockIdx.y;
    const int tid   = threadIdx.x;
    const int f4    = tid & 63;   // which float4 of the 256-feature row
    const int phase = tid >> 6;   // 0..3 row phase

    const float4* Xrow = (const float4*)(X + (size_t)b * N_ * FEAT_);
    float4 acc = make_float4(0.f, 0.f, 0.f, 0.f);

    const int n0 = chunk * ROWS_PER_CHUNK;
    const int n1 = n0 + ROWS_PER_CHUNK;
    for (int n = n0 + phase; n < n1; n += 4) {
        float4 v = Xrow[(size_t)n * (FEAT_ / 4) + f4];
        acc.x += v.x; acc.y += v.y; acc.z += v.z; acc.w += v.w;
    }

    __shared__ float4 sacc[256];
    sacc[tid] = acc;
    __syncthreads();

    if (phase == 0) {
        float4 a = sacc[f4];
        float4 b1 = sacc[64 + f4];
        float4 c = sacc[128 + f4];
        float4 d = sacc[192 + f4];
        float4 t;
        t.x = (a.x + b1.x) + (c.x + d.x);
        t.y = (a.y + b1.y) + (c.y + d.y);
        t.z = (a.z + b1.z) + (c.z + d.z);
        t.w = (a.w + b1.w) + (c.w + d.w);
        ((float4*)part)[((size_t)chunk * B_ + b) * (FEAT_ / 4) + f4] = t;
    }
}

// ---------------------------------------------------------------------------
// Kernel 2: finish. One block per batch, 256 threads.
//   S[b,f]    = sum over chunks of part[c][b][f]
//   out0[b,m] = (S[b,:]·Wv[:,m] + N*bv[m]) / U
//   out[b,m2] = relu(out0[b,:]·Wo[:,m2] + bo[m2])
// ---------------------------------------------------------------------------
__global__ __launch_bounds__(256) void finish_kernel(
    const float* __restrict__ part,
    const float* __restrict__ Wv, const float* __restrict__ bv,
    const float* __restrict__ Wo, const float* __restrict__ bo,
    float* __restrict__ out) {
    const int b   = blockIdx.x;
    const int tid = threadIdx.x;

    __shared__ float sX[FEAT_];
    __shared__ float sO[MEM_];

    // Deterministic fixed-order reduction of the 64 chunk partials.
    float s = 0.f;
    for (int c = 0; c < NCHUNK; ++c)
        s += part[((size_t)c * B_ + b) * FEAT_ + tid];
    sX[tid] = s;
    __syncthreads();

    if (tid < MEM_) {
        float acc = (float)N_ * bv[tid];
        #pragma unroll 8
        for (int f = 0; f < FEAT_; ++f)
            acc = fmaf(sX[f], Wv[f * MEM_ + tid], acc);
        sO[tid] = acc * (1.0f / (float)U_);
    }
    __syncthreads();

    if (tid < MEM_) {
        float acc = bo[tid];
        #pragma unroll 8
        for (int m = 0; m < MEM_; ++m)
            acc = fmaf(sO[m], Wo[m * MEM_ + tid], acc);
        out[b * MEM_ + tid] = fmaxf(acc, 0.f);
    }
}

// ---------------------------------------------------------------------------
extern "C" void kernel_launch(void* const* d_in, const int* in_sizes, int n_in,
                              void* d_out, int out_size, void* d_ws, size_t ws_size,
                              hipStream_t stream) {
    const float* X  = (const float*)d_in[0];
    // d_in[1] = mem, d_in[2] = Wk, d_in[3] = bk  -- mathematically dead
    const float* Wv = (const float*)d_in[4];
    const float* bv = (const float*)d_in[5];
    const float* Wo = (const float*)d_in[6];
    const float* bo = (const float*)d_in[7];
    float* out  = (float*)d_out;
    float* part = (float*)d_ws;   // NCHUNK*B*FEAT floats = 1 MiB

    dim3 g1(NCHUNK, B_);
    colsum_partial<<<g1, 256, 0, stream>>>(X, part);
    finish_kernel<<<B_, 256, 0, stream>>>(part, Wv, bv, Wo, bo, out);
}

// Round 2
// 32.711 us; speedup vs baseline: 1.2359x; 1.2359x over previous
//
#include <hip/hip_runtime.h>

// Problem constants (from reference)
#define B_    16
#define N_    8192
#define FEAT_ 256
#define MEM_  128
#define U_    512

#define NCHUNK 64
#define ROWS_PER_CHUNK (N_ / NCHUNK)   // 128 rows per block

// ---------------------------------------------------------------------------
// Exact algebraic reduction of the reference:
//   softmax over u followed by mean over u  =>  attn weights sum to 1, so
//   out[b,m] = (1/U) * sum_n V[b,n,m];  V = X@Wv + bv
//   => S[b,f] = sum_n X[b,n,f];  out0 = (S@Wv + N*bv)/U;  out = relu(out0@Wo+bo)
// K, mem, Wk, bk, scores, softmax are all mathematically dead.
// ---------------------------------------------------------------------------

// Kernel 1: partial column sums of X over N.
//   part layout: [B][NCHUNK][FEAT]  (contiguous 64KB per batch for kernel 2)
__global__ __launch_bounds__(256) void colsum_partial(
    const float* __restrict__ X, float* __restrict__ part) {
    const int chunk = blockIdx.x;
    const int b     = blockIdx.y;
    const int tid   = threadIdx.x;
    const int f4    = tid & 63;   // which float4 of the 256-feature row
    const int phase = tid >> 6;   // 0..3 row phase

    const float4* Xrow = (const float4*)(X + (size_t)b * N_ * FEAT_);
    float4 acc = make_float4(0.f, 0.f, 0.f, 0.f);

    const int n0 = chunk * ROWS_PER_CHUNK;
    const int n1 = n0 + ROWS_PER_CHUNK;
    #pragma unroll 4
    for (int n = n0 + phase; n < n1; n += 4) {
        float4 v = Xrow[(size_t)n * (FEAT_ / 4) + f4];
        acc.x += v.x; acc.y += v.y; acc.z += v.z; acc.w += v.w;
    }

    __shared__ float4 sacc[256];
    sacc[tid] = acc;
    __syncthreads();

    if (phase == 0) {
        float4 a = sacc[f4];
        float4 b1 = sacc[64 + f4];
        float4 c = sacc[128 + f4];
        float4 d = sacc[192 + f4];
        float4 t;
        t.x = (a.x + b1.x) + (c.x + d.x);
        t.y = (a.y + b1.y) + (c.y + d.y);
        t.z = (a.z + b1.z) + (c.z + d.z);
        t.w = (a.w + b1.w) + (c.w + d.w);
        ((float4*)part)[((size_t)b * NCHUNK + chunk) * (FEAT_ / 4) + f4] = t;
    }
}

// ---------------------------------------------------------------------------
// Kernel 2: finish. One block per batch, 256 threads.
// All weight reads staged to LDS so the dependent FMA chains run at LDS
// latency instead of global latency. 2-way split dot products.
// LDS: 128KB weights + ~6KB aux  ->  1 block/CU (only 16 blocks anyway).
// ---------------------------------------------------------------------------
__global__ __launch_bounds__(256) void finish_kernel(
    const float* __restrict__ part,
    const float* __restrict__ Wv, const float* __restrict__ bv,
    const float* __restrict__ Wo, const float* __restrict__ bo,
    float* __restrict__ out) {
    const int b   = blockIdx.x;
    const int tid = threadIdx.x;

    __shared__ float  sW[FEAT_ * MEM_];   // 128 KB, reused for Wo (64 KB)
    __shared__ float4 sP4[4][FEAT_ / 4];  // 4 KB chunk partials
    __shared__ float  sX[FEAT_];          // 1 KB
    __shared__ float  sO[MEM_];           // 512 B
    __shared__ float  sH[2][MEM_];        // 1 KB half-dot partials

    // --- A) stage Wv -> LDS (coalesced float4, 32 independent loads/thread)
    {
        const float4* wv4 = (const float4*)Wv;
        float4* sW4 = (float4*)sW;
        #pragma unroll
        for (int i = 0; i < (FEAT_ * MEM_ / 4) / 256; ++i)   // 32 iters
            sW4[tid + i * 256] = wv4[tid + i * 256];
    }

    // --- B) chunk-reduce S: 4-way split over chunks, float4 over features
    {
        const float4* p4 = (const float4*)(part + (size_t)b * NCHUNK * FEAT_);
        const int f4 = tid & 63;
        const int q  = tid >> 6;
        float4 pr = make_float4(0.f, 0.f, 0.f, 0.f);
        #pragma unroll 4
        for (int c = q; c < NCHUNK; c += 4) {
            float4 v = p4[c * (FEAT_ / 4) + f4];
            pr.x += v.x; pr.y += v.y; pr.z += v.z; pr.w += v.w;
        }
        sP4[q][f4] = pr;
    }
    __syncthreads();   // covers Wv staging + partials

    if (tid < 64) {
        float4 a = sP4[0][tid], b2 = sP4[1][tid], c2 = sP4[2][tid], d2 = sP4[3][tid];
        float4 t;
        t.x = (a.x + b2.x) + (c2.x + d2.x);
        t.y = (a.y + b2.y) + (c2.y + d2.y);
        t.z = (a.z + b2.z) + (c2.z + d2.z);
        t.w = (a.w + b2.w) + (c2.w + d2.w);
        ((float4*)sX)[tid] = t;
    }
    __syncthreads();

    // --- C) matvec1: out0[m] = (sum_f S[f]*Wv[f][m] + N*bv[m]) / U
    const int m = tid & 127;
    const int h = tid >> 7;   // 2-way split of the f range
    {
        float acc = 0.f;
        const int f0 = h * (FEAT_ / 2);
        #pragma unroll 8
        for (int f = f0; f < f0 + FEAT_ / 2; ++f)
            acc = fmaf(sX[f], sW[f * MEM_ + m], acc);
        sH[h][m] = acc;
    }
    __syncthreads();   // sW reads complete beyond this point

    // --- D) stage Wo -> LDS (reuse sW) while tid<128 computes sO
    {
        const float4* wo4 = (const float4*)Wo;
        float4* sW4 = (float4*)sW;
        #pragma unroll
        for (int i = 0; i < (MEM_ * MEM_ / 4) / 256; ++i)    // 16 iters
            sW4[tid + i * 256] = wo4[tid + i * 256];
    }
    if (tid < MEM_)
        sO[tid] = (sH[0][tid] + sH[1][tid] + (float)N_ * bv[tid]) * (1.0f / (float)U_);
    __syncthreads();

    // --- E) matvec2 + relu: out[m2] = relu(sum_m sO[m]*Wo[m][m2] + bo[m2])
    {
        float acc = 0.f;
        const int k0 = h * (MEM_ / 2);
        #pragma unroll 8
        for (int k = k0; k < k0 + MEM_ / 2; ++k)
            acc = fmaf(sO[k], sW[k * MEM_ + m], acc);
        sH[h][m] = acc;
    }
    __syncthreads();

    if (tid < MEM_)
        out[b * MEM_ + tid] = fmaxf(sH[0][tid] + sH[1][tid] + bo[tid], 0.f);
}

// ---------------------------------------------------------------------------
extern "C" void kernel_launch(void* const* d_in, const int* in_sizes, int n_in,
                              void* d_out, int out_size, void* d_ws, size_t ws_size,
                              hipStream_t stream) {
    const float* X  = (const float*)d_in[0];
    // d_in[1] = mem, d_in[2] = Wk, d_in[3] = bk  -- mathematically dead
    const float* Wv = (const float*)d_in[4];
    const float* bv = (const float*)d_in[5];
    const float* Wo = (const float*)d_in[6];
    const float* bo = (const float*)d_in[7];
    float* out  = (float*)d_out;
    float* part = (float*)d_ws;   // B*NCHUNK*FEAT floats = 1 MiB

    dim3 g1(NCHUNK, B_);
    colsum_partial<<<g1, 256, 0, stream>>>(X, part);
    finish_kernel<<<B_, 256, 0, stream>>>(part, Wv, bv, Wo, bo, out);
}